// Round 1
// baseline (1890.513 us; speedup 1.0000x reference)
//
#include <hip/hip_runtime.h>
#include <math.h>

#define B 32
#define T 512
#define D 512
#define H 8
#define DH 64
#define NEGV (-4294967295.0f)   // -(2^32) + 1
#define LN_EPS 1e-8f

// ---------------------------------------------------------------------------
// Kernel 1: QKV projection GEMM.  C[M,N] = X[M,K] @ W[N,K]^T + bias
// M = B*T = 16384, N = K = 512.  blockIdx.z selects Q/K/V.
// 64x64 tile, BK=16, 16x16 threads, 4x4 per-thread accumulation.
// ---------------------------------------------------------------------------
__global__ __launch_bounds__(256) void qkv_gemm(
    const float* __restrict__ queries, const float* __restrict__ keys,
    const float* __restrict__ Wq, const float* __restrict__ bq,
    const float* __restrict__ Wk, const float* __restrict__ bk,
    const float* __restrict__ Wv, const float* __restrict__ bv,
    float* __restrict__ Qo, float* __restrict__ Ko, float* __restrict__ Vo)
{
    const int mat = blockIdx.z;
    const float* X    = (mat == 0) ? queries : keys;
    const float* W    = (mat == 0) ? Wq : (mat == 1) ? Wk : Wv;
    const float* bias = (mat == 0) ? bq : (mat == 1) ? bk : bv;
    float* C          = (mat == 0) ? Qo : (mat == 1) ? Ko : Vo;

    const int bm = blockIdx.x * 64;
    const int bn = blockIdx.y * 64;
    const int tx = threadIdx.x, ty = threadIdx.y;
    const int tid = ty * 16 + tx;

    // padded stride 66: write addr = kk*66+mm -> bank kk*2+mm, conflict-free
    __shared__ float As[16][66];
    __shared__ float Bs[16][66];

    float acc[4][4] = {};

    for (int k0 = 0; k0 < 512; k0 += 16) {
#pragma unroll
        for (int i = 0; i < 4; ++i) {
            int idx = tid + i * 256;      // 0..1023
            int kk = idx & 15;
            int mm = idx >> 4;
            As[kk][mm] = X[(bm + mm) * 512 + k0 + kk];
            Bs[kk][mm] = W[(bn + mm) * 512 + k0 + kk];
        }
        __syncthreads();
#pragma unroll
        for (int kk = 0; kk < 16; ++kk) {
            float a[4], bb[4];
#pragma unroll
            for (int i = 0; i < 4; ++i) a[i]  = As[kk][ty * 4 + i];
#pragma unroll
            for (int j = 0; j < 4; ++j) bb[j] = Bs[kk][tx * 4 + j];
#pragma unroll
            for (int i = 0; i < 4; ++i)
#pragma unroll
                for (int j = 0; j < 4; ++j)
                    acc[i][j] += a[i] * bb[j];
        }
        __syncthreads();
    }

#pragma unroll
    for (int i = 0; i < 4; ++i) {
        int m = bm + ty * 4 + i;
#pragma unroll
        for (int j = 0; j < 4; ++j) {
            int n = bn + tx * 4 + j;
            C[m * 512 + n] = acc[i][j] + bias[n];
        }
    }
}

// ---------------------------------------------------------------------------
// Kernel 2: row-sum masks.  mask = (sum(row) != 0) ? 1 : 0
// grid (B*T/4, 2); one wave per row. z=0 -> queries->qmask, z=1 -> keys->kmask
// ---------------------------------------------------------------------------
__global__ __launch_bounds__(256) void row_masks(
    const float* __restrict__ queries, const float* __restrict__ keys,
    float* __restrict__ qmask, float* __restrict__ kmask)
{
    const int tid = threadIdx.x;
    const int wid = tid >> 6;
    const int lane = tid & 63;
    const int row = blockIdx.x * 4 + wid;
    const float* src = blockIdx.y ? keys : queries;
    float* dst = blockIdx.y ? kmask : qmask;

    const float4* p = (const float4*)(src + (size_t)row * 512);
    float4 a = p[lane * 2];
    float4 c = p[lane * 2 + 1];
    float s = a.x + a.y + a.z + a.w + c.x + c.y + c.z + c.w;
#pragma unroll
    for (int off = 32; off > 0; off >>= 1) s += __shfl_xor(s, off, 64);
    if (lane == 0) dst[row] = (s != 0.0f) ? 1.0f : 0.0f;
}

// ---------------------------------------------------------------------------
// Kernel 3: attention (all heads for one query row) + residual + LayerNorm.
// One block (256 thr = 4 waves) per row (b,q).  Each wave does 2 heads.
// ---------------------------------------------------------------------------
__device__ inline float wave_max(float v) {
#pragma unroll
    for (int off = 32; off > 0; off >>= 1) v = fmaxf(v, __shfl_xor(v, off, 64));
    return v;
}
__device__ inline float wave_sum(float v) {
#pragma unroll
    for (int off = 32; off > 0; off >>= 1) v += __shfl_xor(v, off, 64);
    return v;
}

__global__ __launch_bounds__(256) void attn_ln(
    const float* __restrict__ Q, const float* __restrict__ K,
    const float* __restrict__ V, const float* __restrict__ queries,
    const float* __restrict__ qmask, const float* __restrict__ kmask,
    const float* __restrict__ gamma, const float* __restrict__ beta,
    float* __restrict__ out)
{
    const int row = blockIdx.x;        // b*T + q
    const int b = row >> 9;
    const int q = row & 511;
    const int tid = threadIdx.x;
    const int wid = tid >> 6;
    const int lane = tid & 63;

    __shared__ float q_lds[512];
    __shared__ float o_lds[512];
    __shared__ float p_lds[4][512];
    __shared__ float red[4];

    // load this row's Q (all heads) into LDS
    for (int i = tid; i < 128; i += 256)
        ((float4*)q_lds)[i] = ((const float4*)(Q + (size_t)row * 512))[i];
    __syncthreads();

    const float* Kb = K + (size_t)b * T * 512;
    const float* Vb = V + (size_t)b * T * 512;
    const float* km = kmask + b * T;
    const float qm = qmask[row];

#pragma unroll
    for (int hi = 0; hi < 2; ++hi) {       // uniform across waves
        const int h = wid + hi * 4;
        const int hoff = h * 64;

        // ---- scores: lane handles k = lane + 64*j ----
        float s[8];
#pragma unroll
        for (int j = 0; j < 8; ++j) {
            int k = lane + j * 64;
            float val = NEGV;
            if (k <= q && km[k] != 0.0f) {
                const float4* kp = (const float4*)(Kb + (size_t)k * 512 + hoff);
                const float4* qp = (const float4*)(q_lds + hoff);
                float acc = 0.0f;
#pragma unroll
                for (int d4 = 0; d4 < 16; ++d4) {
                    float4 kv = kp[d4];
                    float4 qv = qp[d4];
                    acc += kv.x * qv.x + kv.y * qv.y + kv.z * qv.z + kv.w * qv.w;
                }
                val = acc * 0.125f;   // 1/sqrt(64)
            }
            s[j] = val;
        }

        // ---- softmax over 512 entries (wave-local) ----
        float m = s[0];
#pragma unroll
        for (int j = 1; j < 8; ++j) m = fmaxf(m, s[j]);
        m = wave_max(m);
        float e[8], sum = 0.0f;
#pragma unroll
        for (int j = 0; j < 8; ++j) { e[j] = expf(s[j] - m); sum += e[j]; }
        sum = wave_sum(sum);
        float inv = 1.0f / sum;
#pragma unroll
        for (int j = 0; j < 8; ++j) p_lds[wid][lane + j * 64] = e[j] * inv;
        __syncthreads();   // uniform; orders p_lds writes before reads

        // degenerate all-masked row -> uniform softmax over all 512 keys
        const int kend = (m < -4.0e9f) ? 512 : (q + 1);

        // ---- PV: lane = output dim d ----
        const float* vp = Vb + hoff + lane;
        float o = 0.0f;
        const float* pw = p_lds[wid];
#pragma unroll 4
        for (int k = 0; k < kend; ++k)
            o += pw[k] * vp[(size_t)k * 512];
        o_lds[hoff + lane] = o * qm;
        __syncthreads();   // protects p_lds reuse + o_lds completion
    }

    // ---- residual + LayerNorm over the 512-dim row ----
    const float* qrow = queries + (size_t)row * 512;
    float x0 = o_lds[tid]       + qrow[tid];
    float x1 = o_lds[tid + 256] + qrow[tid + 256];

    float part = wave_sum(x0 + x1);
    if (lane == 0) red[wid] = part;
    __syncthreads();
    float mean = (red[0] + red[1] + red[2] + red[3]) * (1.0f / 512.0f);
    __syncthreads();

    float d0 = x0 - mean, d1 = x1 - mean;
    part = wave_sum(d0 * d0 + d1 * d1);
    if (lane == 0) red[wid] = part;
    __syncthreads();
    float var = (red[0] + red[1] + red[2] + red[3]) * (1.0f / 511.0f);
    float denom = sqrtf(var) + LN_EPS;

    out[(size_t)row * 512 + tid]       = gamma[tid]       * d0 / denom + beta[tid];
    out[(size_t)row * 512 + tid + 256] = gamma[tid + 256] * d1 / denom + beta[tid + 256];
}

// ---------------------------------------------------------------------------
extern "C" void kernel_launch(void* const* d_in, const int* in_sizes, int n_in,
                              void* d_out, int out_size, void* d_ws, size_t ws_size,
                              hipStream_t stream)
{
    const float* queries = (const float*)d_in[0];
    const float* keys    = (const float*)d_in[1];
    const float* Wq      = (const float*)d_in[2];
    const float* bq      = (const float*)d_in[3];
    const float* Wk      = (const float*)d_in[4];
    const float* bk      = (const float*)d_in[5];
    const float* Wv      = (const float*)d_in[6];
    const float* bv      = (const float*)d_in[7];
    const float* gamma   = (const float*)d_in[8];
    const float* beta    = (const float*)d_in[9];
    float* out = (float*)d_out;

    float* ws = (float*)d_ws;
    float* Qb    = ws;                    // 8388608 floats (32 MB)
    float* Kb    = ws + 8388608;          // 32 MB
    float* Vb    = ws + 16777216;         // 32 MB
    float* qmask = ws + 25165824;         // 16384 floats
    float* kmask = qmask + 16384;         // 16384 floats

    qkv_gemm<<<dim3(256, 8, 3), dim3(16, 16), 0, stream>>>(
        queries, keys, Wq, bq, Wk, bk, Wv, bv, Qb, Kb, Vb);
    row_masks<<<dim3(4096, 2), 256, 0, stream>>>(queries, keys, qmask, kmask);
    attn_ln<<<16384, 256, 0, stream>>>(
        Qb, Kb, Vb, queries, qmask, kmask, gamma, beta, out);
}

// Round 2
// 570.596 us; speedup vs baseline: 3.3132x; 3.3132x over previous
//
#include <hip/hip_runtime.h>
#include <hip/hip_bf16.h>
#include <math.h>

#define B 32
#define T 512
#define D 512
#define H 8
#define DH 64
#define NEGV (-4294967295.0f)   // -(2^32) + 1
#define LN_EPS 1e-8f

typedef __attribute__((ext_vector_type(8))) short bf16x8;
typedef __attribute__((ext_vector_type(4))) float f32x4;

__device__ inline f32x4 mfma16(bf16x8 a, bf16x8 b, f32x4 c) {
    return __builtin_amdgcn_mfma_f32_16x16x32_bf16(a, b, c, 0, 0, 0);
}

// ---------------------------------------------------------------------------
// Kernel 1: QKV projection GEMM (f32 compute, bf16 outputs).
// C[M,N] = X[M,K] @ W[N,K]^T + bias.  M = B*T = 16384, N = K = 512.
// mat 0 -> Qbf (scaled by 1/8), mat 1 -> Kbf, mat 2 -> Vt transposed [b,h,d,t].
// ---------------------------------------------------------------------------
__global__ __launch_bounds__(256) void qkv_gemm(
    const float* __restrict__ queries, const float* __restrict__ keys,
    const float* __restrict__ Wq, const float* __restrict__ bq,
    const float* __restrict__ Wk, const float* __restrict__ bk,
    const float* __restrict__ Wv, const float* __restrict__ bv,
    __hip_bfloat16* __restrict__ Qbf, __hip_bfloat16* __restrict__ Kbf,
    __hip_bfloat16* __restrict__ Vt)
{
    const int mat = blockIdx.z;
    const float* X    = (mat == 0) ? queries : keys;
    const float* W    = (mat == 0) ? Wq : (mat == 1) ? Wk : Wv;
    const float* bias = (mat == 0) ? bq : (mat == 1) ? bk : bv;

    const int bm = blockIdx.x * 64;
    const int bn = blockIdx.y * 64;
    const int tx = threadIdx.x, ty = threadIdx.y;
    const int tid = ty * 16 + tx;

    __shared__ float As[16][66];
    __shared__ float Bs[16][66];

    float acc[4][4] = {};

    for (int k0 = 0; k0 < 512; k0 += 16) {
#pragma unroll
        for (int i = 0; i < 4; ++i) {
            int idx = tid + i * 256;
            int kk = idx & 15;
            int mm = idx >> 4;
            As[kk][mm] = X[(bm + mm) * 512 + k0 + kk];
            Bs[kk][mm] = W[(bn + mm) * 512 + k0 + kk];
        }
        __syncthreads();
#pragma unroll
        for (int kk = 0; kk < 16; ++kk) {
            float a[4], bb[4];
#pragma unroll
            for (int i = 0; i < 4; ++i) a[i]  = As[kk][ty * 4 + i];
#pragma unroll
            for (int j = 0; j < 4; ++j) bb[j] = Bs[kk][tx * 4 + j];
#pragma unroll
            for (int i = 0; i < 4; ++i)
#pragma unroll
                for (int j = 0; j < 4; ++j)
                    acc[i][j] += a[i] * bb[j];
        }
        __syncthreads();
    }

    float bv4[4];
#pragma unroll
    for (int j = 0; j < 4; ++j) bv4[j] = bias[bn + tx * 4 + j];

    if (mat == 0) {
#pragma unroll
        for (int i = 0; i < 4; ++i) {
            int m = bm + ty * 4 + i;
            union { ushort4 u; __hip_bfloat16 h[4]; } pk;
#pragma unroll
            for (int j = 0; j < 4; ++j)
                pk.h[j] = __float2bfloat16((acc[i][j] + bv4[j]) * 0.125f);
            *(ushort4*)&Qbf[(size_t)m * 512 + bn + tx * 4] = pk.u;
        }
    } else if (mat == 1) {
#pragma unroll
        for (int i = 0; i < 4; ++i) {
            int m = bm + ty * 4 + i;
            union { ushort4 u; __hip_bfloat16 h[4]; } pk;
#pragma unroll
            for (int j = 0; j < 4; ++j)
                pk.h[j] = __float2bfloat16(acc[i][j] + bv4[j]);
            *(ushort4*)&Kbf[(size_t)m * 512 + bn + tx * 4] = pk.u;
        }
    } else {
        const int bb = bm >> 9;            // batch
        const int t0 = (bm & 511) + ty * 4; // token within batch
#pragma unroll
        for (int j = 0; j < 4; ++j) {
            int n = bn + tx * 4 + j;       // full d index 0..511
            int hh = n >> 6, dh = n & 63;
            union { ushort4 u; __hip_bfloat16 h[4]; } pk;
#pragma unroll
            for (int i = 0; i < 4; ++i)
                pk.h[i] = __float2bfloat16(acc[i][j] + bv4[j]);
            *(ushort4*)&Vt[((size_t)(bb * 8 + hh) * 64 + dh) * 512 + t0] = pk.u;
        }
    }
}

// ---------------------------------------------------------------------------
// Kernel 2: row-sum masks.
// ---------------------------------------------------------------------------
__global__ __launch_bounds__(256) void row_masks(
    const float* __restrict__ queries, const float* __restrict__ keys,
    float* __restrict__ qmask, float* __restrict__ kmask)
{
    const int tid = threadIdx.x;
    const int wid = tid >> 6;
    const int lane = tid & 63;
    const int row = blockIdx.x * 4 + wid;
    const float* src = blockIdx.y ? keys : queries;
    float* dst = blockIdx.y ? kmask : qmask;

    const float4* p = (const float4*)(src + (size_t)row * 512);
    float4 a = p[lane * 2];
    float4 c = p[lane * 2 + 1];
    float s = a.x + a.y + a.z + a.w + c.x + c.y + c.z + c.w;
#pragma unroll
    for (int off = 32; off > 0; off >>= 1) s += __shfl_xor(s, off, 64);
    if (lane == 0) dst[row] = (s != 0.0f) ? 1.0f : 0.0f;
}

// ---------------------------------------------------------------------------
// Kernel 3: flash attention, bf16 MFMA 16x16x32.
// Block = (qtile, h, b), 4 waves, each wave owns 16 q rows.
// ---------------------------------------------------------------------------
__global__ __launch_bounds__(256) void flash_attn(
    const __hip_bfloat16* __restrict__ Qbf, const __hip_bfloat16* __restrict__ Kbf,
    const __hip_bfloat16* __restrict__ Vt, const float* __restrict__ qmask,
    const float* __restrict__ kmask, float* __restrict__ Oattn)
{
    const int qtile = blockIdx.x;   // 0..7
    const int h     = blockIdx.y;   // 0..7
    const int b     = blockIdx.z;   // 0..31
    const int tid  = threadIdx.x;
    const int w    = tid >> 6;
    const int lane = tid & 63;
    const int lo = lane & 15;       // MFMA col index
    const int hi = lane >> 4;       // MFMA k-octet / row-group
    const int qbase = qtile * 64 + w * 16;

    __shared__ __hip_bfloat16 p_lds[4][16][88];   // pad 88: 16B-aligned rows, ~2-way banks

    // Q A-fragments (scale already folded in)
    const __hip_bfloat16* Qrow = Qbf + (size_t)(b * T + qbase + lo) * D + h * DH;
    bf16x8 qf0 = *(const bf16x8*)(Qrow + hi * 8);
    bf16x8 qf1 = *(const bf16x8*)(Qrow + 32 + hi * 8);

    f32x4 o[4];
    float m[4], l[4];
#pragma unroll
    for (int d = 0; d < 4; ++d) o[d] = (f32x4){0.f, 0.f, 0.f, 0.f};
#pragma unroll
    for (int j = 0; j < 4; ++j) { m[j] = -INFINITY; l[j] = 0.f; }

    const float* km = kmask + b * T;
    const __hip_bfloat16* Kh = Kbf + (size_t)b * T * D + h * DH;
    const __hip_bfloat16* Vh = Vt + (size_t)(b * H + h) * DH * T;

    for (int kt = 0; kt <= qtile; ++kt) {
        const int kb = kt * 64;

        // ---- S = Q K^T, 4 chunks of 16 keys ----
        f32x4 S[4];
#pragma unroll
        for (int c = 0; c < 4; ++c) {
            const int key = kb + c * 16 + lo;
            const __hip_bfloat16* Krow = Kh + (size_t)key * D;
            bf16x8 kf0 = *(const bf16x8*)(Krow + hi * 8);
            bf16x8 kf1 = *(const bf16x8*)(Krow + 32 + hi * 8);
            f32x4 acc = (f32x4){0.f, 0.f, 0.f, 0.f};
            acc = mfma16(qf0, kf0, acc);
            acc = mfma16(qf1, kf1, acc);
            const float kmv = km[key];
#pragma unroll
            for (int j = 0; j < 4; ++j) {
                int qr = qbase + hi * 4 + j;
                acc[j] = (key <= qr && kmv != 0.0f) ? acc[j] : NEGV;
            }
            S[c] = acc;
        }

        // ---- online softmax (rows live in 16-lane groups) ----
        float tm[4];
#pragma unroll
        for (int j = 0; j < 4; ++j)
            tm[j] = fmaxf(fmaxf(S[0][j], S[1][j]), fmaxf(S[2][j], S[3][j]));
#pragma unroll
        for (int off = 1; off < 16; off <<= 1)
#pragma unroll
            for (int j = 0; j < 4; ++j)
                tm[j] = fmaxf(tm[j], __shfl_xor(tm[j], off, 64));

        float alpha[4];
#pragma unroll
        for (int j = 0; j < 4; ++j) {
            float nm = fmaxf(m[j], tm[j]);
            alpha[j] = __expf(m[j] - nm);
            m[j] = nm;
        }
#pragma unroll
        for (int d = 0; d < 4; ++d)
#pragma unroll
            for (int j = 0; j < 4; ++j)
                o[d][j] *= alpha[j];

        float ps[4] = {0.f, 0.f, 0.f, 0.f};
#pragma unroll
        for (int c = 0; c < 4; ++c) {
#pragma unroll
            for (int j = 0; j < 4; ++j) {
                float p = __expf(S[c][j] - m[j]);
                ps[j] += p;
                p_lds[w][hi * 4 + j][c * 16 + lo] = __float2bfloat16(p);
            }
        }
#pragma unroll
        for (int off = 1; off < 16; off <<= 1)
#pragma unroll
            for (int j = 0; j < 4; ++j)
                ps[j] += __shfl_xor(ps[j], off, 64);
#pragma unroll
        for (int j = 0; j < 4; ++j) l[j] = l[j] * alpha[j] + ps[j];

        __syncthreads();   // order P writes before A-frag reads (uniform loop)

        // ---- O += P V ----
#pragma unroll
        for (int half = 0; half < 2; ++half) {
            bf16x8 pf = *(const bf16x8*)&p_lds[w][lo][half * 32 + hi * 8];
            const __hip_bfloat16* Vk = Vh + kb + half * 32 + hi * 8;
#pragma unroll
            for (int d = 0; d < 4; ++d)
                o[d] = mfma16(pf, *(const bf16x8*)(Vk + (size_t)(d * 16 + lo) * T), o[d]);
        }
        __syncthreads();   // protect p_lds before next tile overwrites
    }

    // ---- epilogue: divide by l, apply query mask, store f32 ----
    float inv[4];
#pragma unroll
    for (int j = 0; j < 4; ++j)
        inv[j] = qmask[b * T + qbase + hi * 4 + j] / l[j];
#pragma unroll
    for (int d = 0; d < 4; ++d)
#pragma unroll
        for (int j = 0; j < 4; ++j)
            Oattn[(size_t)(b * T + qbase + hi * 4 + j) * D + h * DH + d * 16 + lo]
                = o[d][j] * inv[j];
}

// ---------------------------------------------------------------------------
// Kernel 4: residual + LayerNorm (ddof=1, eps added to std).
// ---------------------------------------------------------------------------
__device__ inline float wave_sum(float v) {
#pragma unroll
    for (int off = 32; off > 0; off >>= 1) v += __shfl_xor(v, off, 64);
    return v;
}

__global__ __launch_bounds__(256) void resid_ln(
    const float* __restrict__ Oattn, const float* __restrict__ queries,
    const float* __restrict__ gamma, const float* __restrict__ beta,
    float* __restrict__ out)
{
    const int row = blockIdx.x;
    const int tid = threadIdx.x;
    const int wid = tid >> 6;
    const int lane = tid & 63;
    __shared__ float red[4];

    float x0 = Oattn[(size_t)row * 512 + tid]       + queries[(size_t)row * 512 + tid];
    float x1 = Oattn[(size_t)row * 512 + tid + 256] + queries[(size_t)row * 512 + tid + 256];

    float part = wave_sum(x0 + x1);
    if (lane == 0) red[wid] = part;
    __syncthreads();
    float mean = (red[0] + red[1] + red[2] + red[3]) * (1.0f / 512.0f);
    __syncthreads();

    float d0 = x0 - mean, d1 = x1 - mean;
    part = wave_sum(d0 * d0 + d1 * d1);
    if (lane == 0) red[wid] = part;
    __syncthreads();
    float var = (red[0] + red[1] + red[2] + red[3]) * (1.0f / 511.0f);
    float denom = sqrtf(var) + LN_EPS;

    out[(size_t)row * 512 + tid]       = gamma[tid]       * d0 / denom + beta[tid];
    out[(size_t)row * 512 + tid + 256] = gamma[tid + 256] * d1 / denom + beta[tid + 256];
}

// ---------------------------------------------------------------------------
extern "C" void kernel_launch(void* const* d_in, const int* in_sizes, int n_in,
                              void* d_out, int out_size, void* d_ws, size_t ws_size,
                              hipStream_t stream)
{
    const float* queries = (const float*)d_in[0];
    const float* keys    = (const float*)d_in[1];
    const float* Wq      = (const float*)d_in[2];
    const float* bq      = (const float*)d_in[3];
    const float* Wk      = (const float*)d_in[4];
    const float* bk      = (const float*)d_in[5];
    const float* Wv      = (const float*)d_in[6];
    const float* bv      = (const float*)d_in[7];
    const float* gamma   = (const float*)d_in[8];
    const float* beta    = (const float*)d_in[9];
    float* out = (float*)d_out;

    char* ws = (char*)d_ws;
    __hip_bfloat16* Qbf = (__hip_bfloat16*)(ws);                    // 16 MB
    __hip_bfloat16* Kbf = (__hip_bfloat16*)(ws + 16777216);         // 16 MB
    __hip_bfloat16* Vt  = (__hip_bfloat16*)(ws + 33554432);         // 16 MB
    float* Oattn        = (float*)(ws + 50331648);                  // 32 MB
    float* qmask        = (float*)(ws + 83886080);                  // 64 KB
    float* kmask        = (float*)(ws + 83951616);                  // 64 KB

    qkv_gemm<<<dim3(256, 8, 3), dim3(16, 16), 0, stream>>>(
        queries, keys, Wq, bq, Wk, bk, Wv, bv, Qbf, Kbf, Vt);
    row_masks<<<dim3(4096, 2), 256, 0, stream>>>(queries, keys, qmask, kmask);
    flash_attn<<<dim3(8, 8, 32), 256, 0, stream>>>(
        Qbf, Kbf, Vt, qmask, kmask, Oattn);
    resid_ln<<<16384, 256, 0, stream>>>(Oattn, queries, gamma, beta, out);
}

// Round 3
// 207.851 us; speedup vs baseline: 9.0955x; 2.7452x over previous
//
#include <hip/hip_runtime.h>
#include <hip/hip_bf16.h>
#include <math.h>

#define B 32
#define T 512
#define D 512
#define H 8
#define DH 64
#define NEGV (-4294967295.0f)   // -(2^32) + 1
#define LN_EPS 1e-8f

typedef __attribute__((ext_vector_type(8))) short bf16x8;
typedef __attribute__((ext_vector_type(4))) float f32x4;

__device__ inline f32x4 mfma16(bf16x8 a, bf16x8 b, f32x4 c) {
    return __builtin_amdgcn_mfma_f32_16x16x32_bf16(a, b, c, 0, 0, 0);
}

#define GLDS16(g, l)                                                      \
    __builtin_amdgcn_global_load_lds(                                     \
        (const __attribute__((address_space(1))) void*)(g),               \
        (__attribute__((address_space(3))) void*)(l), 16, 0, 0)

__device__ inline unsigned short bf16bits(float x) {
    __hip_bfloat16 h = __float2bfloat16(x);
    union { __hip_bfloat16 h; unsigned short u; } cv;
    cv.h = h;
    return cv.u;
}

// ---------------------------------------------------------------------------
// Kernel 1: convert queries/keys f32 -> bf16 AND compute row masks.
// grid (B*T/4, 2); wave per row.
// ---------------------------------------------------------------------------
__global__ __launch_bounds__(256) void convert_mask(
    const float* __restrict__ queries, const float* __restrict__ keys,
    __hip_bfloat16* __restrict__ Qx, __hip_bfloat16* __restrict__ Kx,
    float* __restrict__ qmask, float* __restrict__ kmask)
{
    const int tid = threadIdx.x;
    const int wid = tid >> 6;
    const int lane = tid & 63;
    const int row = blockIdx.x * 4 + wid;
    const float* src = blockIdx.y ? keys : queries;
    __hip_bfloat16* dst = blockIdx.y ? Kx : Qx;
    float* dm = blockIdx.y ? kmask : qmask;

    const float4* p = (const float4*)(src + (size_t)row * 512);
    float4 a = p[lane * 2];
    float4 c = p[lane * 2 + 1];
    float s = a.x + a.y + a.z + a.w + c.x + c.y + c.z + c.w;

    union { unsigned short u[8]; bf16x8 v; } pk;
    pk.u[0] = bf16bits(a.x); pk.u[1] = bf16bits(a.y);
    pk.u[2] = bf16bits(a.z); pk.u[3] = bf16bits(a.w);
    pk.u[4] = bf16bits(c.x); pk.u[5] = bf16bits(c.y);
    pk.u[6] = bf16bits(c.z); pk.u[7] = bf16bits(c.w);
    *(bf16x8*)&dst[(size_t)row * 512 + lane * 8] = pk.v;

#pragma unroll
    for (int off = 32; off > 0; off >>= 1) s += __shfl_xor(s, off, 64);
    if (lane == 0) dm[row] = (s != 0.0f) ? 1.0f : 0.0f;
}

// ---------------------------------------------------------------------------
// Kernel 2: convert Wq/Wk/Wv f32 -> bf16 into Wbf[3][512][512].
// ---------------------------------------------------------------------------
__global__ __launch_bounds__(256) void convert_w(
    const float* __restrict__ Wq, const float* __restrict__ Wk,
    const float* __restrict__ Wv, __hip_bfloat16* __restrict__ Wbf)
{
    const int mat = blockIdx.y;
    const float* Ws = (mat == 0) ? Wq : (mat == 1) ? Wk : Wv;
    const int i = (blockIdx.x * 256 + threadIdx.x) * 8;
    float4 a = *(const float4*)&Ws[i];
    float4 c = *(const float4*)&Ws[i + 4];
    union { unsigned short u[8]; bf16x8 v; } pk;
    pk.u[0] = bf16bits(a.x); pk.u[1] = bf16bits(a.y);
    pk.u[2] = bf16bits(a.z); pk.u[3] = bf16bits(a.w);
    pk.u[4] = bf16bits(c.x); pk.u[5] = bf16bits(c.y);
    pk.u[6] = bf16bits(c.z); pk.u[7] = bf16bits(c.w);
    *(bf16x8*)&Wbf[(size_t)mat * 262144 + i] = pk.v;
}

// ---------------------------------------------------------------------------
// Kernel 3: QKV projection, bf16 MFMA.  C[M,N] = X[M,K] @ W[N,K]^T + bias.
// 128x128 tile, BK=32, 4 waves 2x2 (64x64 each), double-buffered LDS via
// global_load_lds(16B).  XOR swizzle: element (row, g*8+e) lives at
// row*32 + (g^(row&3))*8 + e  (applied at stage source AND ds_read).
// ---------------------------------------------------------------------------
__global__ __launch_bounds__(256) void qkv_mfma(
    const __hip_bfloat16* __restrict__ Qx, const __hip_bfloat16* __restrict__ Kx,
    const __hip_bfloat16* __restrict__ Wbf,
    const float* __restrict__ bq, const float* __restrict__ bk,
    const float* __restrict__ bv,
    __hip_bfloat16* __restrict__ Qbf, __hip_bfloat16* __restrict__ Kbf,
    __hip_bfloat16* __restrict__ Vt)
{
    const int mat = blockIdx.z;
    const __hip_bfloat16* X  = (mat == 0) ? Qx : Kx;
    const __hip_bfloat16* Wm = Wbf + (size_t)mat * 262144;
    const float* bias = (mat == 0) ? bq : (mat == 1) ? bk : bv;

    const int bm = blockIdx.x * 128;
    const int bn = blockIdx.y * 128;
    const int tid = threadIdx.x;
    const int w = tid >> 6, lane = tid & 63;
    const int lo = lane & 15, hi = lane >> 4;
    const int wm = (w >> 1) * 64, wn = (w & 1) * 64;

    __shared__ __hip_bfloat16 As[2][128 * 32];
    __shared__ __hip_bfloat16 Bs[2][128 * 32];

    // staging: granules G0 = tid (i=0), G1 = tid+256 (i=1); dest is linear,
    // source reads the swizzle-inverse granule so LDS holds swizzled layout.
    const int r0 = tid >> 2,          g0 = (tid & 3) ^ (r0 & 3);
    const int r1 = (tid + 256) >> 2,  g1 = ((tid + 256) & 3) ^ (r1 & 3);
    const __hip_bfloat16* sA0 = X  + (size_t)(bm + r0) * 512 + g0 * 8;
    const __hip_bfloat16* sA1 = X  + (size_t)(bm + r1) * 512 + g1 * 8;
    const __hip_bfloat16* sB0 = Wm + (size_t)(bn + r0) * 512 + g0 * 8;
    const __hip_bfloat16* sB1 = Wm + (size_t)(bn + r1) * 512 + g1 * 8;
    const int dst0 = (w * 64) * 8;          // elem offset, lane offset is HW-added
    const int dst1 = (256 + w * 64) * 8;

    // fragment ds_read offsets (swizzled), constant per thread
    int offA[4], offB[4];
#pragma unroll
    for (int mi = 0; mi < 4; ++mi) {
        int r = wm + mi * 16 + lo;
        offA[mi] = r * 32 + ((hi ^ (r & 3)) * 8);
    }
#pragma unroll
    for (int ni = 0; ni < 4; ++ni) {
        int r = wn + ni * 16 + lo;
        offB[ni] = r * 32 + ((hi ^ (r & 3)) * 8);
    }

    f32x4 acc[4][4];
#pragma unroll
    for (int mi = 0; mi < 4; ++mi)
#pragma unroll
        for (int ni = 0; ni < 4; ++ni)
            acc[mi][ni] = (f32x4){0.f, 0.f, 0.f, 0.f};

    // prologue: stage k-tile 0 into buf 0
    GLDS16(sA0, &As[0][dst0]);
    GLDS16(sA1, &As[0][dst1]);
    GLDS16(sB0, &Bs[0][dst0]);
    GLDS16(sB1, &Bs[0][dst1]);
    __syncthreads();

    for (int kt = 0; kt < 16; ++kt) {
        const int cur = kt & 1;
        if (kt < 15) {
            const int k0 = (kt + 1) * 32;
            GLDS16(sA0 + k0, &As[cur ^ 1][dst0]);
            GLDS16(sA1 + k0, &As[cur ^ 1][dst1]);
            GLDS16(sB0 + k0, &Bs[cur ^ 1][dst0]);
            GLDS16(sB1 + k0, &Bs[cur ^ 1][dst1]);
        }
        bf16x8 af[4], bfr[4];
#pragma unroll
        for (int mi = 0; mi < 4; ++mi) af[mi]  = *(const bf16x8*)&As[cur][offA[mi]];
#pragma unroll
        for (int ni = 0; ni < 4; ++ni) bfr[ni] = *(const bf16x8*)&Bs[cur][offB[ni]];
#pragma unroll
        for (int mi = 0; mi < 4; ++mi)
#pragma unroll
            for (int ni = 0; ni < 4; ++ni)
                acc[mi][ni] = mfma16(af[mi], bfr[ni], acc[mi][ni]);
        __syncthreads();   // drains vmcnt (next buf staged) + lgkm (reads done)
    }

    // ---- epilogue: bias, per-mat transform, bf16 store ----
    float bcol[4];
#pragma unroll
    for (int ni = 0; ni < 4; ++ni) bcol[ni] = bias[bn + wn + ni * 16 + lo];

    if (mat == 2) {
        const int bb = bm >> 9;
        const int tb = (bm & 511) + wm;
#pragma unroll
        for (int ni = 0; ni < 4; ++ni) {
            const int n = bn + wn + ni * 16 + lo;
            __hip_bfloat16* dcol =
                Vt + ((size_t)(bb * 8 + (n >> 6)) * 64 + (n & 63)) * 512 + tb;
#pragma unroll
            for (int mi = 0; mi < 4; ++mi) {
                union { ushort4 u4; unsigned short us[4]; } pk;
#pragma unroll
                for (int j = 0; j < 4; ++j)
                    pk.us[j] = bf16bits(acc[mi][ni][j] + bcol[ni]);
                *(ushort4*)(dcol + mi * 16 + hi * 4) = pk.u4;
            }
        }
    } else {
        __hip_bfloat16* Out = (mat == 0) ? Qbf : Kbf;
        const float sc = (mat == 0) ? 0.125f : 1.0f;
#pragma unroll
        for (int mi = 0; mi < 4; ++mi)
#pragma unroll
            for (int j = 0; j < 4; ++j) {
                const size_t m = bm + wm + mi * 16 + hi * 4 + j;
                __hip_bfloat16* orow = Out + m * 512 + bn + wn + lo;
#pragma unroll
                for (int ni = 0; ni < 4; ++ni) {
                    __hip_bfloat16 hv;
                    union { __hip_bfloat16 h; unsigned short u; } cv;
                    cv.u = bf16bits((acc[mi][ni][j] + bcol[ni]) * sc);
                    orow[ni * 16] = cv.h;
                }
            }
    }
}

// ---------------------------------------------------------------------------
// Kernel 4: flash attention, bf16 MFMA 16x16x32.  Oattn output is bf16.
// ---------------------------------------------------------------------------
__global__ __launch_bounds__(256) void flash_attn(
    const __hip_bfloat16* __restrict__ Qbf, const __hip_bfloat16* __restrict__ Kbf,
    const __hip_bfloat16* __restrict__ Vt, const float* __restrict__ qmask,
    const float* __restrict__ kmask, __hip_bfloat16* __restrict__ Oattn)
{
    const int qtile = blockIdx.x;
    const int h     = blockIdx.y;
    const int b     = blockIdx.z;
    const int tid  = threadIdx.x;
    const int w    = tid >> 6;
    const int lane = tid & 63;
    const int lo = lane & 15;
    const int hi = lane >> 4;
    const int qbase = qtile * 64 + w * 16;

    __shared__ __hip_bfloat16 p_lds[4][16][88];

    const __hip_bfloat16* Qrow = Qbf + (size_t)(b * T + qbase + lo) * D + h * DH;
    bf16x8 qf0 = *(const bf16x8*)(Qrow + hi * 8);
    bf16x8 qf1 = *(const bf16x8*)(Qrow + 32 + hi * 8);

    f32x4 o[4];
    float m[4], l[4];
#pragma unroll
    for (int d = 0; d < 4; ++d) o[d] = (f32x4){0.f, 0.f, 0.f, 0.f};
#pragma unroll
    for (int j = 0; j < 4; ++j) { m[j] = -INFINITY; l[j] = 0.f; }

    const float* km = kmask + b * T;
    const __hip_bfloat16* Kh = Kbf + (size_t)b * T * D + h * DH;
    const __hip_bfloat16* Vh = Vt + (size_t)(b * H + h) * DH * T;

    for (int kt = 0; kt <= qtile; ++kt) {
        const int kb = kt * 64;

        f32x4 S[4];
#pragma unroll
        for (int c = 0; c < 4; ++c) {
            const int key = kb + c * 16 + lo;
            const __hip_bfloat16* Krow = Kh + (size_t)key * D;
            bf16x8 kf0 = *(const bf16x8*)(Krow + hi * 8);
            bf16x8 kf1 = *(const bf16x8*)(Krow + 32 + hi * 8);
            f32x4 acc = (f32x4){0.f, 0.f, 0.f, 0.f};
            acc = mfma16(qf0, kf0, acc);
            acc = mfma16(qf1, kf1, acc);
            const float kmv = km[key];
#pragma unroll
            for (int j = 0; j < 4; ++j) {
                int qr = qbase + hi * 4 + j;
                acc[j] = (key <= qr && kmv != 0.0f) ? acc[j] : NEGV;
            }
            S[c] = acc;
        }

        float tm[4];
#pragma unroll
        for (int j = 0; j < 4; ++j)
            tm[j] = fmaxf(fmaxf(S[0][j], S[1][j]), fmaxf(S[2][j], S[3][j]));
#pragma unroll
        for (int off = 1; off < 16; off <<= 1)
#pragma unroll
            for (int j = 0; j < 4; ++j)
                tm[j] = fmaxf(tm[j], __shfl_xor(tm[j], off, 64));

        float alpha[4];
#pragma unroll
        for (int j = 0; j < 4; ++j) {
            float nm = fmaxf(m[j], tm[j]);
            alpha[j] = __expf(m[j] - nm);
            m[j] = nm;
        }
#pragma unroll
        for (int d = 0; d < 4; ++d)
#pragma unroll
            for (int j = 0; j < 4; ++j)
                o[d][j] *= alpha[j];

        float ps[4] = {0.f, 0.f, 0.f, 0.f};
#pragma unroll
        for (int c = 0; c < 4; ++c) {
#pragma unroll
            for (int j = 0; j < 4; ++j) {
                float p = __expf(S[c][j] - m[j]);
                ps[j] += p;
                p_lds[w][hi * 4 + j][c * 16 + lo] = __float2bfloat16(p);
            }
        }
#pragma unroll
        for (int off = 1; off < 16; off <<= 1)
#pragma unroll
            for (int j = 0; j < 4; ++j)
                ps[j] += __shfl_xor(ps[j], off, 64);
#pragma unroll
        for (int j = 0; j < 4; ++j) l[j] = l[j] * alpha[j] + ps[j];

        __syncthreads();

#pragma unroll
        for (int half = 0; half < 2; ++half) {
            bf16x8 pf = *(const bf16x8*)&p_lds[w][lo][half * 32 + hi * 8];
            const __hip_bfloat16* Vk = Vh + kb + half * 32 + hi * 8;
#pragma unroll
            for (int d = 0; d < 4; ++d)
                o[d] = mfma16(pf, *(const bf16x8*)(Vk + (size_t)(d * 16 + lo) * T), o[d]);
        }
        __syncthreads();
    }

    float inv[4];
#pragma unroll
    for (int j = 0; j < 4; ++j)
        inv[j] = qmask[b * T + qbase + hi * 4 + j] / l[j];
#pragma unroll
    for (int d = 0; d < 4; ++d)
#pragma unroll
        for (int j = 0; j < 4; ++j)
            Oattn[(size_t)(b * T + qbase + hi * 4 + j) * D + h * DH + d * 16 + lo]
                = __float2bfloat16(o[d][j] * inv[j]);
}

// ---------------------------------------------------------------------------
// Kernel 5: residual + LayerNorm (ddof=1, eps added to std).  Oattn is bf16.
// ---------------------------------------------------------------------------
__device__ inline float wave_sum(float v) {
#pragma unroll
    for (int off = 32; off > 0; off >>= 1) v += __shfl_xor(v, off, 64);
    return v;
}

__global__ __launch_bounds__(256) void resid_ln(
    const __hip_bfloat16* __restrict__ Oa, const float* __restrict__ queries,
    const float* __restrict__ gamma, const float* __restrict__ beta,
    float* __restrict__ out)
{
    const int row = blockIdx.x;
    const int tid = threadIdx.x;
    const int wid = tid >> 6;
    const int lane = tid & 63;
    __shared__ float red[4];

    const size_t base = (size_t)row * 512;
    float2 qv = *(const float2*)&queries[base + 2 * tid];
    unsigned ov = *(const unsigned*)((const unsigned short*)Oa + base + 2 * tid);
    union { unsigned u; float f; } c0, c1;
    c0.u = ov << 16;
    c1.u = ov & 0xffff0000u;
    float x0 = c0.f + qv.x;
    float x1 = c1.f + qv.y;

    float part = wave_sum(x0 + x1);
    if (lane == 0) red[wid] = part;
    __syncthreads();
    float mean = (red[0] + red[1] + red[2] + red[3]) * (1.0f / 512.0f);
    __syncthreads();

    float d0 = x0 - mean, d1 = x1 - mean;
    part = wave_sum(d0 * d0 + d1 * d1);
    if (lane == 0) red[wid] = part;
    __syncthreads();
    float var = (red[0] + red[1] + red[2] + red[3]) * (1.0f / 511.0f);
    float denom = sqrtf(var) + LN_EPS;

    float2 g = *(const float2*)&gamma[2 * tid];
    float2 be = *(const float2*)&beta[2 * tid];
    float2 res;
    res.x = g.x * d0 / denom + be.x;
    res.y = g.y * d1 / denom + be.y;
    *(float2*)&out[base + 2 * tid] = res;
}

// ---------------------------------------------------------------------------
extern "C" void kernel_launch(void* const* d_in, const int* in_sizes, int n_in,
                              void* d_out, int out_size, void* d_ws, size_t ws_size,
                              hipStream_t stream)
{
    const float* queries = (const float*)d_in[0];
    const float* keys    = (const float*)d_in[1];
    const float* Wq      = (const float*)d_in[2];
    const float* bq      = (const float*)d_in[3];
    const float* Wk      = (const float*)d_in[4];
    const float* bk      = (const float*)d_in[5];
    const float* Wv      = (const float*)d_in[6];
    const float* bv      = (const float*)d_in[7];
    const float* gamma   = (const float*)d_in[8];
    const float* beta    = (const float*)d_in[9];
    float* out = (float*)d_out;

    char* ws = (char*)d_ws;
    __hip_bfloat16* Qbf   = (__hip_bfloat16*)(ws);                  // 16 MB
    __hip_bfloat16* Kbf   = (__hip_bfloat16*)(ws + 16777216);       // 16 MB
    __hip_bfloat16* Vt    = (__hip_bfloat16*)(ws + 33554432);       // 16 MB
    __hip_bfloat16* Qx    = (__hip_bfloat16*)(ws + 50331648);       // 16 MB
    __hip_bfloat16* Oattn = (__hip_bfloat16*)(ws + 50331648);       // aliases Qx (dead)
    __hip_bfloat16* Kx    = (__hip_bfloat16*)(ws + 67108864);       // 16 MB
    __hip_bfloat16* Wbf   = (__hip_bfloat16*)(ws + 83886080);       // 1.5 MB
    float* qmask          = (float*)(ws + 85458944);                // 64 KB
    float* kmask          = (float*)(ws + 85524480);                // 64 KB

    convert_mask<<<dim3(4096, 2), 256, 0, stream>>>(
        queries, keys, Qx, Kx, qmask, kmask);
    convert_w<<<dim3(128, 3), 256, 0, stream>>>(Wq, Wk, Wv, Wbf);
    qkv_mfma<<<dim3(128, 4, 3), 256, 0, stream>>>(
        Qx, Kx, Wbf, bq, bk, bv, Qbf, Kbf, Vt);
    flash_attn<<<dim3(8, 8, 32), 256, 0, stream>>>(
        Qbf, Kbf, Vt, qmask, kmask, Oattn);
    resid_ln<<<16384, 256, 0, stream>>>(Oattn, queries, gamma, beta, out);
}

// Round 4
// 159.313 us; speedup vs baseline: 11.8667x; 1.3047x over previous
//
#include <hip/hip_runtime.h>
#include <hip/hip_bf16.h>
#include <math.h>

#define B 32
#define T 512
#define D 512
#define H 8
#define DH 64
#define NEGV (-4294967295.0f)   // -(2^32) + 1
#define LN_EPS 1e-8f

typedef __attribute__((ext_vector_type(8))) short bf16x8;
typedef __attribute__((ext_vector_type(4))) float f32x4;

__device__ inline f32x4 mfma16(bf16x8 a, bf16x8 b, f32x4 c) {
    return __builtin_amdgcn_mfma_f32_16x16x32_bf16(a, b, c, 0, 0, 0);
}

#define GLDS16(g, l)                                                      \
    __builtin_amdgcn_global_load_lds(                                     \
        (const __attribute__((address_space(1))) void*)(g),               \
        (__attribute__((address_space(3))) void*)(l), 16, 0, 0)

__device__ inline unsigned short bf16bits(float x) {
    __hip_bfloat16 h = __float2bfloat16(x);
    union { __hip_bfloat16 h; unsigned short u; } cv;
    cv.h = h;
    return cv.u;
}

// ---------------------------------------------------------------------------
// Kernel 1: convert queries/keys f32 -> bf16 AND compute row masks.
// ---------------------------------------------------------------------------
__global__ __launch_bounds__(256) void convert_mask(
    const float* __restrict__ queries, const float* __restrict__ keys,
    __hip_bfloat16* __restrict__ Qx, __hip_bfloat16* __restrict__ Kx,
    float* __restrict__ qmask, float* __restrict__ kmask)
{
    const int tid = threadIdx.x;
    const int wid = tid >> 6;
    const int lane = tid & 63;
    const int row = blockIdx.x * 4 + wid;
    const float* src = blockIdx.y ? keys : queries;
    __hip_bfloat16* dst = blockIdx.y ? Kx : Qx;
    float* dm = blockIdx.y ? kmask : qmask;

    const float4* p = (const float4*)(src + (size_t)row * 512);
    float4 a = p[lane * 2];
    float4 c = p[lane * 2 + 1];
    float s = a.x + a.y + a.z + a.w + c.x + c.y + c.z + c.w;

    union { unsigned short u[8]; bf16x8 v; } pk;
    pk.u[0] = bf16bits(a.x); pk.u[1] = bf16bits(a.y);
    pk.u[2] = bf16bits(a.z); pk.u[3] = bf16bits(a.w);
    pk.u[4] = bf16bits(c.x); pk.u[5] = bf16bits(c.y);
    pk.u[6] = bf16bits(c.z); pk.u[7] = bf16bits(c.w);
    *(bf16x8*)&dst[(size_t)row * 512 + lane * 8] = pk.v;

#pragma unroll
    for (int off = 32; off > 0; off >>= 1) s += __shfl_xor(s, off, 64);
    if (lane == 0) dm[row] = (s != 0.0f) ? 1.0f : 0.0f;
}

// ---------------------------------------------------------------------------
// Kernel 2: convert Wq/Wk/Wv f32 -> bf16 into Wbf[3][512][512].
// ---------------------------------------------------------------------------
__global__ __launch_bounds__(256) void convert_w(
    const float* __restrict__ Wq, const float* __restrict__ Wk,
    const float* __restrict__ Wv, __hip_bfloat16* __restrict__ Wbf)
{
    const int mat = blockIdx.y;
    const float* Ws = (mat == 0) ? Wq : (mat == 1) ? Wk : Wv;
    const int i = (blockIdx.x * 256 + threadIdx.x) * 8;
    float4 a = *(const float4*)&Ws[i];
    float4 c = *(const float4*)&Ws[i + 4];
    union { unsigned short u[8]; bf16x8 v; } pk;
    pk.u[0] = bf16bits(a.x); pk.u[1] = bf16bits(a.y);
    pk.u[2] = bf16bits(a.z); pk.u[3] = bf16bits(a.w);
    pk.u[4] = bf16bits(c.x); pk.u[5] = bf16bits(c.y);
    pk.u[6] = bf16bits(c.z); pk.u[7] = bf16bits(c.w);
    *(bf16x8*)&Wbf[(size_t)mat * 262144 + i] = pk.v;
}

// ---------------------------------------------------------------------------
// Kernel 3: QKV projection, bf16 MFMA.  C[M,N] = X[M,K] @ W[N,K]^T + bias.
// 128x128 tile, BK=32, 4 waves 2x2, double-buffered LDS via global_load_lds.
// mat 0 -> Qbf (scaled 1/8), mat 1 -> Kbf,
// mat 2 -> Vtb tile-blocked: [b][h][kt][dh][64 tokens].
// ---------------------------------------------------------------------------
__global__ __launch_bounds__(256) void qkv_mfma(
    const __hip_bfloat16* __restrict__ Qx, const __hip_bfloat16* __restrict__ Kx,
    const __hip_bfloat16* __restrict__ Wbf,
    const float* __restrict__ bq, const float* __restrict__ bk,
    const float* __restrict__ bv,
    __hip_bfloat16* __restrict__ Qbf, __hip_bfloat16* __restrict__ Kbf,
    __hip_bfloat16* __restrict__ Vtb)
{
    const int mat = blockIdx.z;
    const __hip_bfloat16* X  = (mat == 0) ? Qx : Kx;
    const __hip_bfloat16* Wm = Wbf + (size_t)mat * 262144;
    const float* bias = (mat == 0) ? bq : (mat == 1) ? bk : bv;

    const int bm = blockIdx.x * 128;
    const int bn = blockIdx.y * 128;
    const int tid = threadIdx.x;
    const int w = tid >> 6, lane = tid & 63;
    const int lo = lane & 15, hi = lane >> 4;
    const int wm = (w >> 1) * 64, wn = (w & 1) * 64;

    __shared__ __hip_bfloat16 As[2][128 * 32];
    __shared__ __hip_bfloat16 Bs[2][128 * 32];

    const int r0 = tid >> 2,          g0 = (tid & 3) ^ (r0 & 3);
    const int r1 = (tid + 256) >> 2,  g1 = ((tid + 256) & 3) ^ (r1 & 3);
    const __hip_bfloat16* sA0 = X  + (size_t)(bm + r0) * 512 + g0 * 8;
    const __hip_bfloat16* sA1 = X  + (size_t)(bm + r1) * 512 + g1 * 8;
    const __hip_bfloat16* sB0 = Wm + (size_t)(bn + r0) * 512 + g0 * 8;
    const __hip_bfloat16* sB1 = Wm + (size_t)(bn + r1) * 512 + g1 * 8;
    const int dst0 = (w * 64) * 8;
    const int dst1 = (256 + w * 64) * 8;

    int offA[4], offB[4];
#pragma unroll
    for (int mi = 0; mi < 4; ++mi) {
        int r = wm + mi * 16 + lo;
        offA[mi] = r * 32 + ((hi ^ (r & 3)) * 8);
    }
#pragma unroll
    for (int ni = 0; ni < 4; ++ni) {
        int r = wn + ni * 16 + lo;
        offB[ni] = r * 32 + ((hi ^ (r & 3)) * 8);
    }

    f32x4 acc[4][4];
#pragma unroll
    for (int mi = 0; mi < 4; ++mi)
#pragma unroll
        for (int ni = 0; ni < 4; ++ni)
            acc[mi][ni] = (f32x4){0.f, 0.f, 0.f, 0.f};

    GLDS16(sA0, &As[0][dst0]);
    GLDS16(sA1, &As[0][dst1]);
    GLDS16(sB0, &Bs[0][dst0]);
    GLDS16(sB1, &Bs[0][dst1]);
    __syncthreads();

    for (int kt = 0; kt < 16; ++kt) {
        const int cur = kt & 1;
        if (kt < 15) {
            const int k0 = (kt + 1) * 32;
            GLDS16(sA0 + k0, &As[cur ^ 1][dst0]);
            GLDS16(sA1 + k0, &As[cur ^ 1][dst1]);
            GLDS16(sB0 + k0, &Bs[cur ^ 1][dst0]);
            GLDS16(sB1 + k0, &Bs[cur ^ 1][dst1]);
        }
        bf16x8 af[4], bfr[4];
#pragma unroll
        for (int mi = 0; mi < 4; ++mi) af[mi]  = *(const bf16x8*)&As[cur][offA[mi]];
#pragma unroll
        for (int ni = 0; ni < 4; ++ni) bfr[ni] = *(const bf16x8*)&Bs[cur][offB[ni]];
#pragma unroll
        for (int mi = 0; mi < 4; ++mi)
#pragma unroll
            for (int ni = 0; ni < 4; ++ni)
                acc[mi][ni] = mfma16(af[mi], bfr[ni], acc[mi][ni]);
        __syncthreads();
    }

    float bcol[4];
#pragma unroll
    for (int ni = 0; ni < 4; ++ni) bcol[ni] = bias[bn + wn + ni * 16 + lo];

    if (mat == 2) {
        const int bb = bm >> 9;
        const int tb = (bm & 511) + wm;
#pragma unroll
        for (int ni = 0; ni < 4; ++ni) {
            const int n = bn + wn + ni * 16 + lo;
            const int hh = n >> 6, dh = n & 63;
#pragma unroll
            for (int mi = 0; mi < 4; ++mi) {
                const int tok = tb + mi * 16 + hi * 4;
                const int ktl = tok >> 6, tl = tok & 63;
                union { ushort4 u4; unsigned short us[4]; } pk;
#pragma unroll
                for (int j = 0; j < 4; ++j)
                    pk.us[j] = bf16bits(acc[mi][ni][j] + bcol[ni]);
                *(ushort4*)(Vtb + ((((size_t)(bb * 8 + hh) * 8 + ktl) * 64 + dh) * 64 + tl))
                    = pk.u4;
            }
        }
    } else {
        __hip_bfloat16* Out = (mat == 0) ? Qbf : Kbf;
        const float sc = (mat == 0) ? 0.125f : 1.0f;
#pragma unroll
        for (int mi = 0; mi < 4; ++mi)
#pragma unroll
            for (int j = 0; j < 4; ++j) {
                const size_t m = bm + wm + mi * 16 + hi * 4 + j;
                __hip_bfloat16* orow = Out + m * 512 + bn + wn + lo;
#pragma unroll
                for (int ni = 0; ni < 4; ++ni) {
                    union { __hip_bfloat16 h; unsigned short u; } cv;
                    cv.u = bf16bits((acc[mi][ni][j] + bcol[ni]) * sc);
                    orow[ni * 16] = cv.h;
                }
            }
    }
}

// ---------------------------------------------------------------------------
// Kernel 4: flash attention, bf16 MFMA 16x16x32.
// Block = (pair, h, b), 4 independent waves (NO block barriers).
// Each wave handles 16 q-rows of qtile=pair, then 16 rows of qtile=7-pair:
// uniform 9 k-tiles per wave.  p_lds is strictly per-wave; the write->read
// dependency is same-wave, fenced with lgkmcnt(0)+sched_barrier (rule #18).
// ---------------------------------------------------------------------------
__global__ __launch_bounds__(256) void flash_attn(
    const __hip_bfloat16* __restrict__ Qbf, const __hip_bfloat16* __restrict__ Kbf,
    const __hip_bfloat16* __restrict__ Vtb, const float* __restrict__ qmask,
    const float* __restrict__ kmask, __hip_bfloat16* __restrict__ Oattn)
{
    const int pr = blockIdx.x;      // 0..3
    const int h  = blockIdx.y;
    const int b  = blockIdx.z;
    const int tid  = threadIdx.x;
    const int w    = tid >> 6;
    const int lane = tid & 63;
    const int lo = lane & 15;
    const int hi = lane >> 4;

    __shared__ __hip_bfloat16 p_lds[4][16][88];

    const float* km = kmask + b * T;
    const __hip_bfloat16* Kh = Kbf + (size_t)b * T * D + h * DH;
    const __hip_bfloat16* Vh = Vtb + (size_t)(b * H + h) * T * DH;  // 8 tiles of 4096

    for (int pass = 0; pass < 2; ++pass) {
        const int qtile = pass ? (7 - pr) : pr;
        const int qbase = qtile * 64 + w * 16;

        const __hip_bfloat16* Qrow = Qbf + (size_t)(b * T + qbase + lo) * D + h * DH;
        bf16x8 qf0 = *(const bf16x8*)(Qrow + hi * 8);
        bf16x8 qf1 = *(const bf16x8*)(Qrow + 32 + hi * 8);

        f32x4 o[4];
        float m[4], l[4];
#pragma unroll
        for (int d = 0; d < 4; ++d) o[d] = (f32x4){0.f, 0.f, 0.f, 0.f};
#pragma unroll
        for (int j = 0; j < 4; ++j) { m[j] = -INFINITY; l[j] = 0.f; }

        for (int kt = 0; kt <= qtile; ++kt) {
            const int kb = kt * 64;

            f32x4 S[4];
#pragma unroll
            for (int c = 0; c < 4; ++c) {
                const int key = kb + c * 16 + lo;
                const __hip_bfloat16* Krow = Kh + (size_t)key * D;
                bf16x8 kf0 = *(const bf16x8*)(Krow + hi * 8);
                bf16x8 kf1 = *(const bf16x8*)(Krow + 32 + hi * 8);
                f32x4 acc = (f32x4){0.f, 0.f, 0.f, 0.f};
                acc = mfma16(qf0, kf0, acc);
                acc = mfma16(qf1, kf1, acc);
                const float kmv = km[key];
#pragma unroll
                for (int j = 0; j < 4; ++j) {
                    int qr = qbase + hi * 4 + j;
                    acc[j] = (key <= qr && kmv != 0.0f) ? acc[j] : NEGV;
                }
                S[c] = acc;
            }

            float tm[4];
#pragma unroll
            for (int j = 0; j < 4; ++j)
                tm[j] = fmaxf(fmaxf(S[0][j], S[1][j]), fmaxf(S[2][j], S[3][j]));
#pragma unroll
            for (int off = 1; off < 16; off <<= 1)
#pragma unroll
                for (int j = 0; j < 4; ++j)
                    tm[j] = fmaxf(tm[j], __shfl_xor(tm[j], off, 64));

            float alpha[4];
#pragma unroll
            for (int j = 0; j < 4; ++j) {
                float nm = fmaxf(m[j], tm[j]);
                alpha[j] = __expf(m[j] - nm);
                m[j] = nm;
            }
#pragma unroll
            for (int d = 0; d < 4; ++d)
#pragma unroll
                for (int j = 0; j < 4; ++j)
                    o[d][j] *= alpha[j];

            float ps[4] = {0.f, 0.f, 0.f, 0.f};
#pragma unroll
            for (int c = 0; c < 4; ++c) {
#pragma unroll
                for (int j = 0; j < 4; ++j) {
                    float p = __expf(S[c][j] - m[j]);
                    ps[j] += p;
                    p_lds[w][hi * 4 + j][c * 16 + lo] = __float2bfloat16(p);
                }
            }
#pragma unroll
            for (int off = 1; off < 16; off <<= 1)
#pragma unroll
                for (int j = 0; j < 4; ++j)
                    ps[j] += __shfl_xor(ps[j], off, 64);
#pragma unroll
            for (int j = 0; j < 4; ++j) l[j] = l[j] * alpha[j] + ps[j];

            // same-wave LDS write -> read fence (p_lds slice is per-wave)
            asm volatile("s_waitcnt lgkmcnt(0)" ::: "memory");
            __builtin_amdgcn_sched_barrier(0);

            const __hip_bfloat16* Vtile = Vh + (size_t)kt * 4096;
#pragma unroll
            for (int half = 0; half < 2; ++half) {
                bf16x8 pf = *(const bf16x8*)&p_lds[w][lo][half * 32 + hi * 8];
#pragma unroll
                for (int d = 0; d < 4; ++d)
                    o[d] = mfma16(pf,
                        *(const bf16x8*)(Vtile + (d * 16 + lo) * 64 + half * 32 + hi * 8),
                        o[d]);
            }
            // reads complete before this wave's next-tile writes issue (in-order DS)
        }

        float inv[4];
#pragma unroll
        for (int j = 0; j < 4; ++j)
            inv[j] = qmask[b * T + qbase + hi * 4 + j] / l[j];
#pragma unroll
        for (int d = 0; d < 4; ++d)
#pragma unroll
            for (int j = 0; j < 4; ++j)
                Oattn[(size_t)(b * T + qbase + hi * 4 + j) * D + h * DH + d * 16 + lo]
                    = __float2bfloat16(o[d][j] * inv[j]);
    }
}

// ---------------------------------------------------------------------------
// Kernel 5: residual + LayerNorm (ddof=1, eps added to std).
// ---------------------------------------------------------------------------
__device__ inline float wave_sum(float v) {
#pragma unroll
    for (int off = 32; off > 0; off >>= 1) v += __shfl_xor(v, off, 64);
    return v;
}

__global__ __launch_bounds__(256) void resid_ln(
    const __hip_bfloat16* __restrict__ Oa, const float* __restrict__ queries,
    const float* __restrict__ gamma, const float* __restrict__ beta,
    float* __restrict__ out)
{
    const int row = blockIdx.x;
    const int tid = threadIdx.x;
    const int wid = tid >> 6;
    const int lane = tid & 63;
    __shared__ float red[4];

    const size_t base = (size_t)row * 512;
    float2 qv = *(const float2*)&queries[base + 2 * tid];
    unsigned ov = *(const unsigned*)((const unsigned short*)Oa + base + 2 * tid);
    union { unsigned u; float f; } c0, c1;
    c0.u = ov << 16;
    c1.u = ov & 0xffff0000u;
    float x0 = c0.f + qv.x;
    float x1 = c1.f + qv.y;

    float part = wave_sum(x0 + x1);
    if (lane == 0) red[wid] = part;
    __syncthreads();
    float mean = (red[0] + red[1] + red[2] + red[3]) * (1.0f / 512.0f);
    __syncthreads();

    float d0 = x0 - mean, d1 = x1 - mean;
    part = wave_sum(d0 * d0 + d1 * d1);
    if (lane == 0) red[wid] = part;
    __syncthreads();
    float var = (red[0] + red[1] + red[2] + red[3]) * (1.0f / 511.0f);
    float denom = sqrtf(var) + LN_EPS;

    float2 g = *(const float2*)&gamma[2 * tid];
    float2 be = *(const float2*)&beta[2 * tid];
    float2 res;
    res.x = g.x * d0 / denom + be.x;
    res.y = g.y * d1 / denom + be.y;
    *(float2*)&out[base + 2 * tid] = res;
}

// ---------------------------------------------------------------------------
extern "C" void kernel_launch(void* const* d_in, const int* in_sizes, int n_in,
                              void* d_out, int out_size, void* d_ws, size_t ws_size,
                              hipStream_t stream)
{
    const float* queries = (const float*)d_in[0];
    const float* keys    = (const float*)d_in[1];
    const float* Wq      = (const float*)d_in[2];
    const float* bq      = (const float*)d_in[3];
    const float* Wk      = (const float*)d_in[4];
    const float* bk      = (const float*)d_in[5];
    const float* Wv      = (const float*)d_in[6];
    const float* bv      = (const float*)d_in[7];
    const float* gamma   = (const float*)d_in[8];
    const float* beta    = (const float*)d_in[9];
    float* out = (float*)d_out;

    char* ws = (char*)d_ws;
    __hip_bfloat16* Qbf   = (__hip_bfloat16*)(ws);                  // 16 MB
    __hip_bfloat16* Kbf   = (__hip_bfloat16*)(ws + 16777216);       // 16 MB
    __hip_bfloat16* Vtb   = (__hip_bfloat16*)(ws + 33554432);       // 16 MB
    __hip_bfloat16* Qx    = (__hip_bfloat16*)(ws + 50331648);       // 16 MB
    __hip_bfloat16* Oattn = (__hip_bfloat16*)(ws + 50331648);       // aliases Qx (dead)
    __hip_bfloat16* Kx    = (__hip_bfloat16*)(ws + 67108864);       // 16 MB
    __hip_bfloat16* Wbf   = (__hip_bfloat16*)(ws + 83886080);       // 1.5 MB
    float* qmask          = (float*)(ws + 85458944);                // 64 KB
    float* kmask          = (float*)(ws + 85524480);                // 64 KB

    convert_mask<<<dim3(4096, 2), 256, 0, stream>>>(
        queries, keys, Qx, Kx, qmask, kmask);
    convert_w<<<dim3(128, 3), 256, 0, stream>>>(Wq, Wk, Wv, Wbf);
    qkv_mfma<<<dim3(128, 4, 3), 256, 0, stream>>>(
        Qx, Kx, Wbf, bq, bk, bv, Qbf, Kbf, Vtb);
    flash_attn<<<dim3(4, 8, 32), 256, 0, stream>>>(
        Qbf, Kbf, Vtb, qmask, kmask, Oattn);
    resid_ln<<<16384, 256, 0, stream>>>(Oattn, queries, gamma, beta, out);
}